// Round 6
// baseline (387.410 us; speedup 1.0000x reference)
//
#include <hip/hip_runtime.h>
#include <math.h>

#define B_    32
#define NPER_ 96
#define M_    3072
#define H_    8
#define CH_   16
#define PQK_  8
#define PV_   12
#define CS_   256
#define CZ_   128
#define E_    294912
#define NCAT_ 1056
#define OF_   432   // padded o_feats row stride (422 real cols)

// ---------------------------------------------------------------------------
// Tiled f32 GEMM (64x64): C[M,N] = A[M,K] @ W[K,N] + bias[N]. W rows >= KW -> 0.
// ---------------------------------------------------------------------------
template <bool ALIGN_A>
__global__ __launch_bounds__(256) void gemm64(const float* __restrict__ A,
                                              const float* __restrict__ W,
                                              const float* __restrict__ bias,
                                              float* __restrict__ C,
                                              int N, int K, int KW) {
  __shared__ float As[16][68];
  __shared__ float Bs[16][64];
  const int tid = threadIdx.x;
  const int tx = tid & 15, ty = tid >> 4;
  const int row0 = blockIdx.y * 64, col0 = blockIdx.x * 64;
  float acc[4][4] = {};

  for (int k0 = 0; k0 < K; k0 += 16) {
    {
      const int m = tid >> 2, k4 = (tid & 3) * 4;
      const int gk = k0 + k4;
      float a0 = 0.f, a1 = 0.f, a2 = 0.f, a3 = 0.f;
      if (ALIGN_A) {
        const float4 av = *reinterpret_cast<const float4*>(A + (size_t)(row0 + m) * K + gk);
        a0 = av.x; a1 = av.y; a2 = av.z; a3 = av.w;
      } else {
        const float* ap = A + (size_t)(row0 + m) * K;
        if (gk + 0 < K) a0 = ap[gk + 0];
        if (gk + 1 < K) a1 = ap[gk + 1];
        if (gk + 2 < K) a2 = ap[gk + 2];
        if (gk + 3 < K) a3 = ap[gk + 3];
      }
      As[k4 + 0][m] = a0; As[k4 + 1][m] = a1; As[k4 + 2][m] = a2; As[k4 + 3][m] = a3;
    }
    {
      const int kk = tid >> 4, n4 = (tid & 15) * 4;
      const int gk = k0 + kk, gn = col0 + n4;
      float4 bv; bv.x = 0.f; bv.y = 0.f; bv.z = 0.f; bv.w = 0.f;
      if (gk < KW) {
        if (gn + 3 < N) {
          bv = *reinterpret_cast<const float4*>(W + (size_t)gk * N + gn);
        } else {
          const float* wp = W + (size_t)gk * N;
          if (gn + 0 < N) bv.x = wp[gn + 0];
          if (gn + 1 < N) bv.y = wp[gn + 1];
          if (gn + 2 < N) bv.z = wp[gn + 2];
          if (gn + 3 < N) bv.w = wp[gn + 3];
        }
      }
      *reinterpret_cast<float4*>(&Bs[kk][n4]) = bv;
    }
    __syncthreads();
#pragma unroll
    for (int kk = 0; kk < 16; ++kk) {
      const float4 a_ = *reinterpret_cast<const float4*>(&As[kk][ty * 4]);
      const float4 b_ = *reinterpret_cast<const float4*>(&Bs[kk][tx * 4]);
      acc[0][0] += a_.x * b_.x; acc[0][1] += a_.x * b_.y; acc[0][2] += a_.x * b_.z; acc[0][3] += a_.x * b_.w;
      acc[1][0] += a_.y * b_.x; acc[1][1] += a_.y * b_.y; acc[1][2] += a_.y * b_.z; acc[1][3] += a_.y * b_.w;
      acc[2][0] += a_.z * b_.x; acc[2][1] += a_.z * b_.y; acc[2][2] += a_.z * b_.z; acc[2][3] += a_.z * b_.w;
      acc[3][0] += a_.w * b_.x; acc[3][1] += a_.w * b_.y; acc[3][2] += a_.w * b_.z; acc[3][3] += a_.w * b_.w;
    }
    __syncthreads();
  }
  const int gn0 = col0 + tx * 4;
#pragma unroll
  for (int i2 = 0; i2 < 4; ++i2) {
    const int gr = row0 + ty * 4 + i2;
    if (gn0 + 3 < N) {
      const float4 bsv = *reinterpret_cast<const float4*>(bias + gn0);
      float4 cv;
      cv.x = acc[i2][0] + bsv.x; cv.y = acc[i2][1] + bsv.y;
      cv.z = acc[i2][2] + bsv.z; cv.w = acc[i2][3] + bsv.w;
      *reinterpret_cast<float4*>(C + (size_t)gr * N + gn0) = cv;
    } else {
#pragma unroll
      for (int j2 = 0; j2 < 4; ++j2) {
        const int gn = gn0 + j2;
        if (gn < N) C[(size_t)gr * N + gn] = acc[i2][j2] + bias[gn];
      }
    }
  }
}

// ---------------------------------------------------------------------------
// Tiled f32 GEMM (128x64, 8x4 micro): better FMA:LDS-read ratio for proj GEMM.
// K must be multiple of 16, A float4-aligned.
// ---------------------------------------------------------------------------
__global__ __launch_bounds__(256) void gemm128(const float* __restrict__ A,
                                               const float* __restrict__ W,
                                               const float* __restrict__ bias,
                                               float* __restrict__ C,
                                               int N, int K) {
  __shared__ float As[16][132];
  __shared__ float Bs[16][64];
  const int tid = threadIdx.x;
  const int tx = tid & 15, ty = tid >> 4;
  const int row0 = blockIdx.y * 128, col0 = blockIdx.x * 64;
  float acc[8][4] = {};

  for (int k0 = 0; k0 < K; k0 += 16) {
#pragma unroll
    for (int u = 0; u < 2; ++u) {  // A tile: 128 rows x 16 k = 512 float4
      const int idx = tid * 2 + u;
      const int r = idx >> 2, c = (idx & 3) * 4;
      const float4 av = *reinterpret_cast<const float4*>(A + (size_t)(row0 + r) * K + k0 + c);
      As[c + 0][r] = av.x; As[c + 1][r] = av.y; As[c + 2][r] = av.z; As[c + 3][r] = av.w;
    }
    {  // B tile: 16 k x 64 n
      const int kk = tid >> 4, n4 = (tid & 15) * 4;
      const int gn = col0 + n4;
      float4 bv; bv.x = 0.f; bv.y = 0.f; bv.z = 0.f; bv.w = 0.f;
      if (gn + 3 < N) {
        bv = *reinterpret_cast<const float4*>(W + (size_t)(k0 + kk) * N + gn);
      } else {
        const float* wp = W + (size_t)(k0 + kk) * N;
        if (gn + 0 < N) bv.x = wp[gn + 0];
        if (gn + 1 < N) bv.y = wp[gn + 1];
        if (gn + 2 < N) bv.z = wp[gn + 2];
        if (gn + 3 < N) bv.w = wp[gn + 3];
      }
      *reinterpret_cast<float4*>(&Bs[kk][n4]) = bv;
    }
    __syncthreads();
#pragma unroll
    for (int kk = 0; kk < 16; ++kk) {
      const float4 a0 = *reinterpret_cast<const float4*>(&As[kk][ty * 8]);
      const float4 a1 = *reinterpret_cast<const float4*>(&As[kk][ty * 8 + 4]);
      const float4 b_ = *reinterpret_cast<const float4*>(&Bs[kk][tx * 4]);
      acc[0][0] += a0.x * b_.x; acc[0][1] += a0.x * b_.y; acc[0][2] += a0.x * b_.z; acc[0][3] += a0.x * b_.w;
      acc[1][0] += a0.y * b_.x; acc[1][1] += a0.y * b_.y; acc[1][2] += a0.y * b_.z; acc[1][3] += a0.y * b_.w;
      acc[2][0] += a0.z * b_.x; acc[2][1] += a0.z * b_.y; acc[2][2] += a0.z * b_.z; acc[2][3] += a0.z * b_.w;
      acc[3][0] += a0.w * b_.x; acc[3][1] += a0.w * b_.y; acc[3][2] += a0.w * b_.z; acc[3][3] += a0.w * b_.w;
      acc[4][0] += a1.x * b_.x; acc[4][1] += a1.x * b_.y; acc[4][2] += a1.x * b_.z; acc[4][3] += a1.x * b_.w;
      acc[5][0] += a1.y * b_.x; acc[5][1] += a1.y * b_.y; acc[5][2] += a1.y * b_.z; acc[5][3] += a1.y * b_.w;
      acc[6][0] += a1.z * b_.x; acc[6][1] += a1.z * b_.y; acc[6][2] += a1.z * b_.z; acc[6][3] += a1.z * b_.w;
      acc[7][0] += a1.w * b_.x; acc[7][1] += a1.w * b_.y; acc[7][2] += a1.w * b_.z; acc[7][3] += a1.w * b_.w;
    }
    __syncthreads();
  }
  const int gn0 = col0 + tx * 4;
#pragma unroll
  for (int i2 = 0; i2 < 8; ++i2) {
    const int gr = row0 + ty * 8 + i2;
    if (gn0 + 3 < N) {
      const float4 bsv = *reinterpret_cast<const float4*>(bias + gn0);
      float4 cv;
      cv.x = acc[i2][0] + bsv.x; cv.y = acc[i2][1] + bsv.y;
      cv.z = acc[i2][2] + bsv.z; cv.w = acc[i2][3] + bsv.w;
      *reinterpret_cast<float4*>(C + (size_t)gr * N + gn0) = cv;
    } else {
#pragma unroll
      for (int j2 = 0; j2 < 4; ++j2) {
        const int gn = gn0 + j2;
        if (gn < N) C[(size_t)gr * N + gn] = acc[i2][j2] + bias[gn];
      }
    }
  }
}

// ---------------------------------------------------------------------------
// Pack the 4 projection weight matrices into Wcat[256][1056] (+ bcat[1056]).
// ---------------------------------------------------------------------------
__global__ __launch_bounds__(256) void pack_w(const float* __restrict__ Wq,
                                              const float* __restrict__ Wkv,
                                              const float* __restrict__ Wqp,
                                              const float* __restrict__ Wkvp,
                                              const float* __restrict__ bq,
                                              const float* __restrict__ bkv,
                                              const float* __restrict__ bqp,
                                              const float* __restrict__ bkvp,
                                              float* __restrict__ Wcat,
                                              float* __restrict__ bcat) {
  const int t = blockIdx.x * 256 + threadIdx.x;
  if (t < 256 * NCAT_) {
    const int k = t / NCAT_, n = t - k * NCAT_;
    float v;
    if (n < 128)      v = Wq [k * 128 + n];
    else if (n < 384) v = Wkv[k * 256 + n - 128];
    else if (n < 576) v = Wqp[k * 192 + n - 384];
    else              v = Wkvp[k * 480 + n - 576];
    Wcat[t] = v;
  }
  if (t < NCAT_) {
    float v;
    if (t < 128)      v = bq[t];
    else if (t < 384) v = bkv[t - 128];
    else if (t < 576) v = bqp[t - 384];
    else              v = bkvp[t - 576];
    bcat[t] = v;
  }
}

// ---------------------------------------------------------------------------
// Rotate raw point projections into global frame; seed o_feats L columns.
// ---------------------------------------------------------------------------
__global__ __launch_bounds__(256) void rotate_pts(const float* __restrict__ praw,
                                                  const float* __restrict__ rot,
                                                  const float* __restrict__ trans,
                                                  const float* __restrict__ L,
                                                  float* __restrict__ qpts,
                                                  float* __restrict__ kpts,
                                                  float* __restrict__ vpts,
                                                  float* __restrict__ ofeat) {
  const int m = blockIdx.x;
  const int t = threadIdx.x;
  float R[9], T[3];
#pragma unroll
  for (int a = 0; a < 9; ++a) R[a] = rot[m * 9 + a];
#pragma unroll
  for (int a = 0; a < 3; ++a) T[a] = trans[m * 3 + a];
  const float* prow = praw + (size_t)m * NCAT_;

  if (t < 64) {
    const float x = prow[384 + t];
    const float y = prow[384 + 64 + t];
    const float z = prow[384 + 128 + t];
    const int h = t >> 3, p = t & 7;
    float* dst = qpts + ((size_t)(m * 8 + h) * 8 + p) * 3;
    dst[0] = R[0] * x + R[1] * y + R[2] * z + T[0];
    dst[1] = R[3] * x + R[4] * y + R[5] * z + T[1];
    dst[2] = R[6] * x + R[7] * y + R[8] * z + T[2];
  } else if (t < 224) {
    const int idx = t - 64;
    const float x = prow[576 + idx];
    const float y = prow[576 + 160 + idx];
    const float z = prow[576 + 320 + idx];
    const int h = idx / 20, p = idx % 20;
    const float o0 = R[0] * x + R[1] * y + R[2] * z + T[0];
    const float o1 = R[3] * x + R[4] * y + R[5] * z + T[1];
    const float o2 = R[6] * x + R[7] * y + R[8] * z + T[2];
    float* dst = (p < 8) ? (kpts + ((size_t)(m * 8 + h) * 8 + p) * 3)
                         : (vpts + ((size_t)(m * 8 + h) * 12 + (p - 8)) * 3);
    dst[0] = o0; dst[1] = o1; dst[2] = o2;
  } else if (t < 230) {
    ofeat[(size_t)m * OF_ + 416 + (t - 224)] = L[(m / NPER_) * 6 + (t - 224)];
  }
}

// ---------------------------------------------------------------------------
// bpair: block = (b, i). Reads 96 CONSECUTIVE z rows (48 KB contiguous).
// Butterfly reduces 8 heads into lanes 0-7; LDS stage [j][h]; flush natural
// layout bT2[h][b][i][j] as 384-B contiguous runs per head. Both sides
// coalesced; no transpose anywhere.
// ---------------------------------------------------------------------------
__global__ __launch_bounds__(256) void bpair_kernel(const float* __restrict__ z,
                                                    const float* __restrict__ Wb,
                                                    const float* __restrict__ bb,
                                                    float* __restrict__ bT2) {
  __shared__ float lds_out[96 * 9];
  const int bid = blockIdx.x;
  const int b = bid / 96, i = bid - b * 96;
  const int l = threadIdx.x & 63;
  const int w = threadIdx.x >> 6;
  const float4* W4 = reinterpret_cast<const float4*>(Wb);
  const float4 w0 = W4[l * 4 + 0];
  const float4 w1 = W4[l * 4 + 1];
  const float4 w2 = W4[l * 4 + 2];
  const float4 w3 = W4[l * 4 + 3];
  const int b0 = l & 1, b1 = (l >> 1) & 1, b2 = (l >> 2) & 1;
  const int myh = (b0 << 2) | (b1 << 1) | b2;
  const float mybb = bb[myh];
  const float2* z2 = reinterpret_cast<const float2*>(z);
  const size_t e0 = (size_t)b * 9216 + (size_t)i * 96;

#pragma unroll 1
  for (int j = w; j < 96; j += 4) {
    const float2 zv = z2[(e0 + j) * 64 + l];
    float a0 = zv.x * w0.x + zv.y * w2.x;
    float a1 = zv.x * w0.y + zv.y * w2.y;
    float a2 = zv.x * w0.z + zv.y * w2.z;
    float a3 = zv.x * w0.w + zv.y * w2.w;
    float a4 = zv.x * w1.x + zv.y * w3.x;
    float a5 = zv.x * w1.y + zv.y * w3.y;
    float a6 = zv.x * w1.z + zv.y * w3.z;
    float a7 = zv.x * w1.w + zv.y * w3.w;
    float s40 = (b0 ? a4 : a0) + __shfl_xor(b0 ? a0 : a4, 1);
    float s41 = (b0 ? a5 : a1) + __shfl_xor(b0 ? a1 : a5, 1);
    float s42 = (b0 ? a6 : a2) + __shfl_xor(b0 ? a2 : a6, 1);
    float s43 = (b0 ? a7 : a3) + __shfl_xor(b0 ? a3 : a7, 1);
    float s20 = (b1 ? s42 : s40) + __shfl_xor(b1 ? s40 : s42, 2);
    float s21 = (b1 ? s43 : s41) + __shfl_xor(b1 ? s41 : s43, 2);
    float s1 = (b2 ? s21 : s20) + __shfl_xor(b2 ? s20 : s21, 4);
    s1 += __shfl_xor(s1, 8);
    s1 += __shfl_xor(s1, 16);
    s1 += __shfl_xor(s1, 32);
    if (l < 8) lds_out[j * 9 + myh] = s1 + mybb;
  }
  __syncthreads();
  for (int idx = threadIdx.x; idx < 768; idx += 256) {
    const int h = idx / 96, j = idx - h * 96;
    bT2[(size_t)h * E_ + e0 + j] = lds_out[j * 9 + h];
  }
}

// ---------------------------------------------------------------------------
// Attention: one block per (batch, head). 768 threads = 96 rows x 8 lanes.
// Bias tile [i][j] staged contiguous (36 KB); read lds_b[i*100+j] (2-way free).
// ---------------------------------------------------------------------------
__global__ __launch_bounds__(768, 3) void attn_kernel(const float* __restrict__ praw,
                                                      const float* __restrict__ qpts,
                                                      const float* __restrict__ kpts,
                                                      const float* __restrict__ vpts,
                                                      const float* __restrict__ bT2,
                                                      const float* __restrict__ L,
                                                      const float* __restrict__ Wl,
                                                      const float* __restrict__ bl,
                                                      const float* __restrict__ hwts,
                                                      float* __restrict__ ofeat) {
  const int b = blockIdx.x >> 3, h = blockIdx.x & 7;
  __shared__ float4 k4[96 * 5];
  __shared__ float4 v4[96 * 5];
  __shared__ float4 kp4[96 * 6];
  __shared__ float4 vp4[96 * 9];
  __shared__ float lds_b[96 * 100];
  const int tid = threadIdx.x;

  {  // k/v: 96 rows x 8 float4, one per thread
    const int i = tid >> 3, c = tid & 7;
    const float4* src = reinterpret_cast<const float4*>(praw + (size_t)(b * 96 + i) * NCAT_ + 128 + h * 32);
    if (c < 4) k4[i * 5 + c] = src[c];
    else       v4[i * 5 + (c - 4)] = src[c];
  }
  for (int t = tid; t < 96 * 6; t += 768) {
    const int i = t / 6, c = t - i * 6;
    kp4[t] = reinterpret_cast<const float4*>(kpts + ((size_t)(b * 96 + i) * 8 + h) * 24)[c];
  }
  for (int t = tid; t < 96 * 9; t += 768) {
    const int i = t / 9, c = t - i * 9;
    vp4[t] = reinterpret_cast<const float4*>(vpts + ((size_t)(b * 96 + i) * 8 + h) * 36)[c];
  }
  {  // bias tile: 9216 floats contiguous [i][j] -> lds_b[i*100 + j]
    const float4* g4 = reinterpret_cast<const float4*>(bT2 + (size_t)h * E_ + (size_t)b * 9216);
    for (int t = tid; t < 2304; t += 768) {
      const int ii = t / 24, c = t - ii * 24;
      reinterpret_cast<float4*>(lds_b + ii * 100)[c] = g4[t];
    }
  }
  __syncthreads();

  const int j = tid >> 3, qq = tid & 7;
  const int mj = b * 96 + j;

  float lb = bl[h];
#pragma unroll
  for (int d = 0; d < 6; ++d) lb += L[b * 6 + d] * Wl[d * 8 + h];
  const float c_l = 0.5f * lb;
  const float sp = logf(1.0f + __expf(hwts[h]));
  const float c_pt = 0.5f * sp * (1.0f / 12.0f);

  const float4* q4 = reinterpret_cast<const float4*>(praw + (size_t)mj * NCAT_ + h * 16);
  const float4 qa = q4[0], qb = q4[1], qc = q4[2], qd = q4[3];
  float qp[24];
  {
    const float4* qp4 = reinterpret_cast<const float4*>(qpts + ((size_t)mj * 8 + h) * 24);
#pragma unroll
    for (int c4 = 0; c4 < 6; ++c4) {
      const float4 v_ = qp4[c4];
      qp[c4 * 4 + 0] = v_.x; qp[c4 * 4 + 1] = v_.y; qp[c4 * 4 + 2] = v_.z; qp[c4 * 4 + 3] = v_.w;
    }
  }

  float lg[12];
  float mx = -3.0e38f;
#pragma unroll
  for (int s = 0; s < 12; ++s) {
    const int i = s * 8 + qq;
    const float4 ka = k4[i * 5 + 0], kb = k4[i * 5 + 1], kc = k4[i * 5 + 2], kd = k4[i * 5 + 3];
    float dot = qa.x * ka.x + qa.y * ka.y + qa.z * ka.z + qa.w * ka.w
              + qb.x * kb.x + qb.y * kb.y + qb.z * kb.z + qb.w * kb.w
              + qc.x * kc.x + qc.y * kc.y + qc.z * kc.z + qc.w * kc.w
              + qd.x * kd.x + qd.y * kd.y + qd.z * kd.z + qd.w * kd.w;
    float pd = 0.f;
#pragma unroll
    for (int c4 = 0; c4 < 6; ++c4) {
      const float4 kp = kp4[i * 6 + c4];
      const float d0 = qp[c4 * 4 + 0] - kp.x;
      const float d1 = qp[c4 * 4 + 1] - kp.y;
      const float d2 = qp[c4 * 4 + 2] - kp.z;
      const float d3 = qp[c4 * 4 + 3] - kp.w;
      pd += d0 * d0 + d1 * d1 + d2 * d2 + d3 * d3;
    }
    const float lv = dot * 0.125f + 0.5f * lds_b[i * 100 + j] + c_l - c_pt * pd;
    lg[s] = lv;
    mx = fmaxf(mx, lv);
  }
  mx = fmaxf(mx, __shfl_xor(mx, 1));
  mx = fmaxf(mx, __shfl_xor(mx, 2));
  mx = fmaxf(mx, __shfl_xor(mx, 4));
  float sum = 0.f;
#pragma unroll
  for (int s = 0; s < 12; ++s) { lg[s] = __expf(lg[s] - mx); sum += lg[s]; }
  sum += __shfl_xor(sum, 1);
  sum += __shfl_xor(sum, 2);
  sum += __shfl_xor(sum, 4);
  const float inv = 1.0f / sum;

  float acco[16] = {};
  float accp[36] = {};
#pragma unroll
  for (int s = 0; s < 12; ++s) {
    const int i = s * 8 + qq;
    const float w = lg[s];
#pragma unroll
    for (int c4 = 0; c4 < 4; ++c4) {
      const float4 vv = v4[i * 5 + c4];
      acco[c4 * 4 + 0] += w * vv.x; acco[c4 * 4 + 1] += w * vv.y;
      acco[c4 * 4 + 2] += w * vv.z; acco[c4 * 4 + 3] += w * vv.w;
    }
#pragma unroll
    for (int c4 = 0; c4 < 9; ++c4) {
      const float4 pv = vp4[i * 9 + c4];
      accp[c4 * 4 + 0] += w * pv.x; accp[c4 * 4 + 1] += w * pv.y;
      accp[c4 * 4 + 2] += w * pv.z; accp[c4 * 4 + 3] += w * pv.w;
    }
  }
#pragma unroll
  for (int u = 0; u < 16; ++u) {
    acco[u] += __shfl_xor(acco[u], 1); acco[u] += __shfl_xor(acco[u], 2); acco[u] += __shfl_xor(acco[u], 4);
  }
#pragma unroll
  for (int u = 0; u < 36; ++u) {
    accp[u] += __shfl_xor(accp[u], 1); accp[u] += __shfl_xor(accp[u], 2); accp[u] += __shfl_xor(accp[u], 4);
  }

  if (qq == 0) {
    float* orow = ofeat + (size_t)mj * OF_;
#pragma unroll
    for (int c = 0; c < 16; ++c) orow[h * 16 + c] = acco[c] * inv;
#pragma unroll
    for (int d = 0; d < 3; ++d)
#pragma unroll
      for (int p = 0; p < 12; ++p)
        orow[128 + d * 96 + h * 12 + p] = accp[p * 3 + d] * inv;
  }
}

// ---------------------------------------------------------------------------
extern "C" void kernel_launch(void* const* d_in, const int* in_sizes, int n_in,
                              void* d_out, int out_size, void* d_ws, size_t ws_size,
                              hipStream_t stream) {
  const float* s     = (const float*)d_in[0];
  const float* z     = (const float*)d_in[1];
  const float* rot   = (const float*)d_in[2];
  const float* trans = (const float*)d_in[3];
  const float* L     = (const float*)d_in[4];
  const float* Wq    = (const float*)d_in[5];
  const float* bq    = (const float*)d_in[6];
  const float* Wkv   = (const float*)d_in[7];
  const float* bkv   = (const float*)d_in[8];
  const float* Wqp   = (const float*)d_in[9];
  const float* bqp   = (const float*)d_in[10];
  const float* Wkvp  = (const float*)d_in[11];
  const float* bkvp  = (const float*)d_in[12];
  const float* Wb    = (const float*)d_in[13];
  const float* bb    = (const float*)d_in[14];
  const float* Wl    = (const float*)d_in[15];
  const float* bl    = (const float*)d_in[16];
  const float* hwts  = (const float*)d_in[17];
  const float* Wout  = (const float*)d_in[18];
  const float* bout  = (const float*)d_in[19];
  float* out = (float*)d_out;
  float* ws  = (float*)d_ws;

  // workspace layout (floats)
  float* praw  = ws;                    // [M,1056]   3244032
  float* qpts  = praw  + 3244032;       // [M,8,8,3]   589824
  float* kpts  = qpts  + 589824;        //             589824
  float* vpts  = kpts  + 589824;        // [M,8,12,3]  884736
  float* ofeat = vpts  + 884736;        // [M,432]    1327104
  float* bT2   = ofeat + 1327104;       // [8,B,96,96] 2359296 (natural [h][b][i][j])
  float* Wcat  = bT2   + 2359296;       // [256,1056]  270336
  float* bcat  = Wcat  + 270336;        // [1056]

  pack_w<<<(256 * NCAT_ + 255) / 256, 256, 0, stream>>>(Wq, Wkv, Wqp, Wkvp, bq, bkv, bqp, bkvp, Wcat, bcat);
  gemm128<<<dim3(17, 24), 256, 0, stream>>>(s, Wcat, bcat, praw, NCAT_, 256);
  rotate_pts<<<M_, 256, 0, stream>>>(praw, rot, trans, L, qpts, kpts, vpts, ofeat);
  bpair_kernel<<<M_, 256, 0, stream>>>(z, Wb, bb, bT2);
  attn_kernel<<<256, 768, 0, stream>>>(praw, qpts, kpts, vpts, bT2, L, Wl, bl, hwts, ofeat);
  gemm64<true ><<<dim3(4, 48), 256, 0, stream>>>(ofeat, Wout, bout, out, 256, OF_, 422);
}

// Round 9
// 366.783 us; speedup vs baseline: 1.0562x; 1.0562x over previous
//
#include <hip/hip_runtime.h>
#include <math.h>

#define B_    32
#define NPER_ 96
#define M_    3072
#define H_    8
#define CH_   16
#define PQK_  8
#define PV_   12
#define CS_   256
#define CZ_   128
#define E_    294912
#define NCAT_ 1056
#define OF_   432   // padded o_feats row stride (422 real cols)
#define GEMM_BLOCKS 816   // 17 col-tiles x 48 row-tiles

// ---------------------------------------------------------------------------
// Tiled f32 GEMM (64x64): C[M,N] = A[M,K] @ W[K,N] + bias[N]. W rows >= KW -> 0.
// Used for the output projection.
// ---------------------------------------------------------------------------
template <bool ALIGN_A>
__global__ __launch_bounds__(256) void gemm64(const float* __restrict__ A,
                                              const float* __restrict__ W,
                                              const float* __restrict__ bias,
                                              float* __restrict__ C,
                                              int N, int K, int KW) {
  __shared__ float As[16][68];
  __shared__ float Bs[16][64];
  const int tid = threadIdx.x;
  const int tx = tid & 15, ty = tid >> 4;
  const int row0 = blockIdx.y * 64, col0 = blockIdx.x * 64;
  float acc[4][4] = {};

  for (int k0 = 0; k0 < K; k0 += 16) {
    {
      const int m = tid >> 2, k4 = (tid & 3) * 4;
      const int gk = k0 + k4;
      float a0 = 0.f, a1 = 0.f, a2 = 0.f, a3 = 0.f;
      if (ALIGN_A) {
        const float4 av = *reinterpret_cast<const float4*>(A + (size_t)(row0 + m) * K + gk);
        a0 = av.x; a1 = av.y; a2 = av.z; a3 = av.w;
      } else {
        const float* ap = A + (size_t)(row0 + m) * K;
        if (gk + 0 < K) a0 = ap[gk + 0];
        if (gk + 1 < K) a1 = ap[gk + 1];
        if (gk + 2 < K) a2 = ap[gk + 2];
        if (gk + 3 < K) a3 = ap[gk + 3];
      }
      As[k4 + 0][m] = a0; As[k4 + 1][m] = a1; As[k4 + 2][m] = a2; As[k4 + 3][m] = a3;
    }
    {
      const int kk = tid >> 4, n4 = (tid & 15) * 4;
      const int gk = k0 + kk, gn = col0 + n4;
      float4 bv; bv.x = 0.f; bv.y = 0.f; bv.z = 0.f; bv.w = 0.f;
      if (gk < KW) {
        if (gn + 3 < N) {
          bv = *reinterpret_cast<const float4*>(W + (size_t)gk * N + gn);
        } else {
          const float* wp = W + (size_t)gk * N;
          if (gn + 0 < N) bv.x = wp[gn + 0];
          if (gn + 1 < N) bv.y = wp[gn + 1];
          if (gn + 2 < N) bv.z = wp[gn + 2];
          if (gn + 3 < N) bv.w = wp[gn + 3];
        }
      }
      *reinterpret_cast<float4*>(&Bs[kk][n4]) = bv;
    }
    __syncthreads();
#pragma unroll
    for (int kk = 0; kk < 16; ++kk) {
      const float4 a_ = *reinterpret_cast<const float4*>(&As[kk][ty * 4]);
      const float4 b_ = *reinterpret_cast<const float4*>(&Bs[kk][tx * 4]);
      acc[0][0] += a_.x * b_.x; acc[0][1] += a_.x * b_.y; acc[0][2] += a_.x * b_.z; acc[0][3] += a_.x * b_.w;
      acc[1][0] += a_.y * b_.x; acc[1][1] += a_.y * b_.y; acc[1][2] += a_.y * b_.z; acc[1][3] += a_.y * b_.w;
      acc[2][0] += a_.z * b_.x; acc[2][1] += a_.z * b_.y; acc[2][2] += a_.z * b_.z; acc[2][3] += a_.z * b_.w;
      acc[3][0] += a_.w * b_.x; acc[3][1] += a_.w * b_.y; acc[3][2] += a_.w * b_.z; acc[3][3] += a_.w * b_.w;
    }
    __syncthreads();
  }
  const int gn0 = col0 + tx * 4;
#pragma unroll
  for (int i2 = 0; i2 < 4; ++i2) {
    const int gr = row0 + ty * 4 + i2;
    if (gn0 + 3 < N) {
      const float4 bsv = *reinterpret_cast<const float4*>(bias + gn0);
      float4 cv;
      cv.x = acc[i2][0] + bsv.x; cv.y = acc[i2][1] + bsv.y;
      cv.z = acc[i2][2] + bsv.z; cv.w = acc[i2][3] + bsv.w;
      *reinterpret_cast<float4*>(C + (size_t)gr * N + gn0) = cv;
    } else {
#pragma unroll
      for (int j2 = 0; j2 < 4; ++j2) {
        const int gn = gn0 + j2;
        if (gn < N) C[(size_t)gr * N + gn] = acc[i2][j2] + bias[gn];
      }
    }
  }
}

// ---------------------------------------------------------------------------
// Fused kernel: blocks [0,816) = projection GEMM (64x64 tile, direct multi-W
// reads — no packed Wcat needed since col-tile boundaries 128/384/576 are
// multiples of 64); blocks [816, 816+3072) = bpair (z @ Wb, HBM-bound).
// Compute-bound and memory-bound blocks co-resident -> overlap.
// ---------------------------------------------------------------------------
__global__ __launch_bounds__(256) void proj_bpair(const float* __restrict__ s,
                                                  const float* __restrict__ Wq,
                                                  const float* __restrict__ Wkv,
                                                  const float* __restrict__ Wqp,
                                                  const float* __restrict__ Wkvp,
                                                  const float* __restrict__ bq,
                                                  const float* __restrict__ bkv,
                                                  const float* __restrict__ bqp,
                                                  const float* __restrict__ bkvp,
                                                  const float* __restrict__ z,
                                                  const float* __restrict__ Wb,
                                                  const float* __restrict__ bb,
                                                  float* __restrict__ praw,
                                                  float* __restrict__ bT2) {
  __shared__ float smem[16 * 68 + 16 * 64];
  const int bid = blockIdx.x;
  const int tid = threadIdx.x;

  if (bid < GEMM_BLOCKS) {
    // ---------------- projection GEMM path ----------------
    float (*As)[68] = reinterpret_cast<float(*)[68]>(smem);
    float (*Bs)[64] = reinterpret_cast<float(*)[64]>(smem + 16 * 68);
    const int cb = bid % 17, rb = bid / 17;
    const int row0 = rb * 64, col0 = cb * 64;
    const float* Wsrc; const float* bsrc; int Nsrc, cbase;
    if (col0 < 128)      { Wsrc = Wq;   bsrc = bq;   Nsrc = 128; cbase = 0; }
    else if (col0 < 384) { Wsrc = Wkv;  bsrc = bkv;  Nsrc = 256; cbase = 128; }
    else if (col0 < 576) { Wsrc = Wqp;  bsrc = bqp;  Nsrc = 192; cbase = 384; }
    else                 { Wsrc = Wkvp; bsrc = bkvp; Nsrc = 480; cbase = 576; }
    const int csrc0 = col0 - cbase;
    const int tx = tid & 15, ty = tid >> 4;
    float acc[4][4] = {};

    for (int k0 = 0; k0 < 256; k0 += 16) {
      {
        const int m = tid >> 2, k4 = (tid & 3) * 4;
        const float4 av = *reinterpret_cast<const float4*>(s + (size_t)(row0 + m) * 256 + k0 + k4);
        As[k4 + 0][m] = av.x; As[k4 + 1][m] = av.y; As[k4 + 2][m] = av.z; As[k4 + 3][m] = av.w;
      }
      {
        const int kk = tid >> 4, n4 = (tid & 15) * 4;
        const int gnl = csrc0 + n4;  // Nsrc % 4 == 0 -> float4 fully in or out
        float4 bv; bv.x = 0.f; bv.y = 0.f; bv.z = 0.f; bv.w = 0.f;
        if (gnl < Nsrc) bv = *reinterpret_cast<const float4*>(Wsrc + (size_t)(k0 + kk) * Nsrc + gnl);
        *reinterpret_cast<float4*>(&Bs[kk][n4]) = bv;
      }
      __syncthreads();
#pragma unroll
      for (int kk = 0; kk < 16; ++kk) {
        const float4 a_ = *reinterpret_cast<const float4*>(&As[kk][ty * 4]);
        const float4 b_ = *reinterpret_cast<const float4*>(&Bs[kk][tx * 4]);
        acc[0][0] += a_.x * b_.x; acc[0][1] += a_.x * b_.y; acc[0][2] += a_.x * b_.z; acc[0][3] += a_.x * b_.w;
        acc[1][0] += a_.y * b_.x; acc[1][1] += a_.y * b_.y; acc[1][2] += a_.y * b_.z; acc[1][3] += a_.y * b_.w;
        acc[2][0] += a_.z * b_.x; acc[2][1] += a_.z * b_.y; acc[2][2] += a_.z * b_.z; acc[2][3] += a_.z * b_.w;
        acc[3][0] += a_.w * b_.x; acc[3][1] += a_.w * b_.y; acc[3][2] += a_.w * b_.z; acc[3][3] += a_.w * b_.w;
      }
      __syncthreads();
    }
    const int gnl0 = csrc0 + tx * 4;
    if (gnl0 < Nsrc) {
      const float4 bsv = *reinterpret_cast<const float4*>(bsrc + gnl0);
#pragma unroll
      for (int i2 = 0; i2 < 4; ++i2) {
        const int gr = row0 + ty * 4 + i2;
        float4 cv;
        cv.x = acc[i2][0] + bsv.x; cv.y = acc[i2][1] + bsv.y;
        cv.z = acc[i2][2] + bsv.z; cv.w = acc[i2][3] + bsv.w;
        *reinterpret_cast<float4*>(praw + (size_t)gr * NCAT_ + col0 + tx * 4) = cv;
      }
    }
  } else {
    // ---------------- bpair path ----------------
    float* lds_out = smem;
    const int eb = bid - GEMM_BLOCKS;
    const int b = eb / 96, i = eb - b * 96;
    const int l = tid & 63;
    const int w = tid >> 6;
    const float4* W4 = reinterpret_cast<const float4*>(Wb);
    const float4 w0 = W4[l * 4 + 0];
    const float4 w1 = W4[l * 4 + 1];
    const float4 w2 = W4[l * 4 + 2];
    const float4 w3 = W4[l * 4 + 3];
    const int b0 = l & 1, b1 = (l >> 1) & 1, b2 = (l >> 2) & 1;
    const int myh = (b0 << 2) | (b1 << 1) | b2;
    const float mybb = bb[myh];
    const float2* z2 = reinterpret_cast<const float2*>(z);
    const size_t e0 = (size_t)b * 9216 + (size_t)i * 96;

#pragma unroll 1
    for (int j = w; j < 96; j += 4) {
      const float2 zv = z2[(e0 + j) * 64 + l];
      float a0 = zv.x * w0.x + zv.y * w2.x;
      float a1 = zv.x * w0.y + zv.y * w2.y;
      float a2 = zv.x * w0.z + zv.y * w2.z;
      float a3 = zv.x * w0.w + zv.y * w2.w;
      float a4 = zv.x * w1.x + zv.y * w3.x;
      float a5 = zv.x * w1.y + zv.y * w3.y;
      float a6 = zv.x * w1.z + zv.y * w3.z;
      float a7 = zv.x * w1.w + zv.y * w3.w;
      float s40 = (b0 ? a4 : a0) + __shfl_xor(b0 ? a0 : a4, 1);
      float s41 = (b0 ? a5 : a1) + __shfl_xor(b0 ? a1 : a5, 1);
      float s42 = (b0 ? a6 : a2) + __shfl_xor(b0 ? a2 : a6, 1);
      float s43 = (b0 ? a7 : a3) + __shfl_xor(b0 ? a3 : a7, 1);
      float s20 = (b1 ? s42 : s40) + __shfl_xor(b1 ? s40 : s42, 2);
      float s21 = (b1 ? s43 : s41) + __shfl_xor(b1 ? s41 : s43, 2);
      float s1 = (b2 ? s21 : s20) + __shfl_xor(b2 ? s20 : s21, 4);
      s1 += __shfl_xor(s1, 8);
      s1 += __shfl_xor(s1, 16);
      s1 += __shfl_xor(s1, 32);
      if (l < 8) lds_out[j * 9 + myh] = s1 + mybb;
    }
    __syncthreads();
    for (int idx = tid; idx < 768; idx += 256) {
      const int h = idx / 96, j = idx - h * 96;
      bT2[(size_t)h * E_ + e0 + j] = lds_out[j * 9 + h];
    }
  }
}

// ---------------------------------------------------------------------------
// Rotate raw point projections into global frame; seed o_feats L columns.
// ---------------------------------------------------------------------------
__global__ __launch_bounds__(256) void rotate_pts(const float* __restrict__ praw,
                                                  const float* __restrict__ rot,
                                                  const float* __restrict__ trans,
                                                  const float* __restrict__ L,
                                                  float* __restrict__ qpts,
                                                  float* __restrict__ kpts,
                                                  float* __restrict__ vpts,
                                                  float* __restrict__ ofeat) {
  const int m = blockIdx.x;
  const int t = threadIdx.x;
  float R[9], T[3];
#pragma unroll
  for (int a = 0; a < 9; ++a) R[a] = rot[m * 9 + a];
#pragma unroll
  for (int a = 0; a < 3; ++a) T[a] = trans[m * 3 + a];
  const float* prow = praw + (size_t)m * NCAT_;

  if (t < 64) {
    const float x = prow[384 + t];
    const float y = prow[384 + 64 + t];
    const float z = prow[384 + 128 + t];
    const int h = t >> 3, p = t & 7;
    float* dst = qpts + ((size_t)(m * 8 + h) * 8 + p) * 3;
    dst[0] = R[0] * x + R[1] * y + R[2] * z + T[0];
    dst[1] = R[3] * x + R[4] * y + R[5] * z + T[1];
    dst[2] = R[6] * x + R[7] * y + R[8] * z + T[2];
  } else if (t < 224) {
    const int idx = t - 64;
    const float x = prow[576 + idx];
    const float y = prow[576 + 160 + idx];
    const float z = prow[576 + 320 + idx];
    const int h = idx / 20, p = idx % 20;
    const float o0 = R[0] * x + R[1] * y + R[2] * z + T[0];
    const float o1 = R[3] * x + R[4] * y + R[5] * z + T[1];
    const float o2 = R[6] * x + R[7] * y + R[8] * z + T[2];
    float* dst = (p < 8) ? (kpts + ((size_t)(m * 8 + h) * 8 + p) * 3)
                         : (vpts + ((size_t)(m * 8 + h) * 12 + (p - 8)) * 3);
    dst[0] = o0; dst[1] = o1; dst[2] = o2;
  } else if (t < 230) {
    ofeat[(size_t)m * OF_ + 416 + (t - 224)] = L[(m / NPER_) * 6 + (t - 224)];
  }
}

// ---------------------------------------------------------------------------
// Attention: one block per (batch, head). 768 threads = 96 rows x 8 lanes.
// Bias tile [i][j] staged contiguous (36 KB); read lds_b[i*100+j] (2-way free).
// ---------------------------------------------------------------------------
__global__ __launch_bounds__(768, 3) void attn_kernel(const float* __restrict__ praw,
                                                      const float* __restrict__ qpts,
                                                      const float* __restrict__ kpts,
                                                      const float* __restrict__ vpts,
                                                      const float* __restrict__ bT2,
                                                      const float* __restrict__ L,
                                                      const float* __restrict__ Wl,
                                                      const float* __restrict__ bl,
                                                      const float* __restrict__ hwts,
                                                      float* __restrict__ ofeat) {
  const int b = blockIdx.x >> 3, h = blockIdx.x & 7;
  __shared__ float4 k4[96 * 5];
  __shared__ float4 v4[96 * 5];
  __shared__ float4 kp4[96 * 6];
  __shared__ float4 vp4[96 * 9];
  __shared__ float lds_b[96 * 100];
  const int tid = threadIdx.x;

  {  // k/v: 96 rows x 8 float4, one per thread
    const int i = tid >> 3, c = tid & 7;
    const float4* src = reinterpret_cast<const float4*>(praw + (size_t)(b * 96 + i) * NCAT_ + 128 + h * 32);
    if (c < 4) k4[i * 5 + c] = src[c];
    else       v4[i * 5 + (c - 4)] = src[c];
  }
  for (int t = tid; t < 96 * 6; t += 768) {
    const int i = t / 6, c = t - i * 6;
    kp4[t] = reinterpret_cast<const float4*>(kpts + ((size_t)(b * 96 + i) * 8 + h) * 24)[c];
  }
  for (int t = tid; t < 96 * 9; t += 768) {
    const int i = t / 9, c = t - i * 9;
    vp4[t] = reinterpret_cast<const float4*>(vpts + ((size_t)(b * 96 + i) * 8 + h) * 36)[c];
  }
  {  // bias tile: 9216 floats contiguous [i][j] -> lds_b[i*100 + j]
    const float4* g4 = reinterpret_cast<const float4*>(bT2 + (size_t)h * E_ + (size_t)b * 9216);
    for (int t = tid; t < 2304; t += 768) {
      const int ii = t / 24, c = t - ii * 24;
      reinterpret_cast<float4*>(lds_b + ii * 100)[c] = g4[t];
    }
  }
  __syncthreads();

  const int j = tid >> 3, qq = tid & 7;
  const int mj = b * 96 + j;

  float lb = bl[h];
#pragma unroll
  for (int d = 0; d < 6; ++d) lb += L[b * 6 + d] * Wl[d * 8 + h];
  const float c_l = 0.5f * lb;
  const float sp = logf(1.0f + __expf(hwts[h]));
  const float c_pt = 0.5f * sp * (1.0f / 12.0f);

  const float4* q4 = reinterpret_cast<const float4*>(praw + (size_t)mj * NCAT_ + h * 16);
  const float4 qa = q4[0], qb = q4[1], qc = q4[2], qd = q4[3];
  float qp[24];
  {
    const float4* qp4 = reinterpret_cast<const float4*>(qpts + ((size_t)mj * 8 + h) * 24);
#pragma unroll
    for (int c4 = 0; c4 < 6; ++c4) {
      const float4 v_ = qp4[c4];
      qp[c4 * 4 + 0] = v_.x; qp[c4 * 4 + 1] = v_.y; qp[c4 * 4 + 2] = v_.z; qp[c4 * 4 + 3] = v_.w;
    }
  }

  float lg[12];
  float mx = -3.0e38f;
#pragma unroll
  for (int s = 0; s < 12; ++s) {
    const int i = s * 8 + qq;
    const float4 ka = k4[i * 5 + 0], kb = k4[i * 5 + 1], kc = k4[i * 5 + 2], kd = k4[i * 5 + 3];
    float dot = qa.x * ka.x + qa.y * ka.y + qa.z * ka.z + qa.w * ka.w
              + qb.x * kb.x + qb.y * kb.y + qb.z * kb.z + qb.w * kb.w
              + qc.x * kc.x + qc.y * kc.y + qc.z * kc.z + qc.w * kc.w
              + qd.x * kd.x + qd.y * kd.y + qd.z * kd.z + qd.w * kd.w;
    float pd = 0.f;
#pragma unroll
    for (int c4 = 0; c4 < 6; ++c4) {
      const float4 kp = kp4[i * 6 + c4];
      const float d0 = qp[c4 * 4 + 0] - kp.x;
      const float d1 = qp[c4 * 4 + 1] - kp.y;
      const float d2 = qp[c4 * 4 + 2] - kp.z;
      const float d3 = qp[c4 * 4 + 3] - kp.w;
      pd += d0 * d0 + d1 * d1 + d2 * d2 + d3 * d3;
    }
    const float lv = dot * 0.125f + 0.5f * lds_b[i * 100 + j] + c_l - c_pt * pd;
    lg[s] = lv;
    mx = fmaxf(mx, lv);
  }
  mx = fmaxf(mx, __shfl_xor(mx, 1));
  mx = fmaxf(mx, __shfl_xor(mx, 2));
  mx = fmaxf(mx, __shfl_xor(mx, 4));
  float sum = 0.f;
#pragma unroll
  for (int s = 0; s < 12; ++s) { lg[s] = __expf(lg[s] - mx); sum += lg[s]; }
  sum += __shfl_xor(sum, 1);
  sum += __shfl_xor(sum, 2);
  sum += __shfl_xor(sum, 4);
  const float inv = 1.0f / sum;

  float acco[16] = {};
  float accp[36] = {};
#pragma unroll
  for (int s = 0; s < 12; ++s) {
    const int i = s * 8 + qq;
    const float w = lg[s];
#pragma unroll
    for (int c4 = 0; c4 < 4; ++c4) {
      const float4 vv = v4[i * 5 + c4];
      acco[c4 * 4 + 0] += w * vv.x; acco[c4 * 4 + 1] += w * vv.y;
      acco[c4 * 4 + 2] += w * vv.z; acco[c4 * 4 + 3] += w * vv.w;
    }
#pragma unroll
    for (int c4 = 0; c4 < 9; ++c4) {
      const float4 pv = vp4[i * 9 + c4];
      accp[c4 * 4 + 0] += w * pv.x; accp[c4 * 4 + 1] += w * pv.y;
      accp[c4 * 4 + 2] += w * pv.z; accp[c4 * 4 + 3] += w * pv.w;
    }
  }
#pragma unroll
  for (int u = 0; u < 16; ++u) {
    acco[u] += __shfl_xor(acco[u], 1); acco[u] += __shfl_xor(acco[u], 2); acco[u] += __shfl_xor(acco[u], 4);
  }
#pragma unroll
  for (int u = 0; u < 36; ++u) {
    accp[u] += __shfl_xor(accp[u], 1); accp[u] += __shfl_xor(accp[u], 2); accp[u] += __shfl_xor(accp[u], 4);
  }

  if (qq == 0) {
    float* orow = ofeat + (size_t)mj * OF_;
#pragma unroll
    for (int c = 0; c < 16; ++c) orow[h * 16 + c] = acco[c] * inv;
#pragma unroll
    for (int d = 0; d < 3; ++d)
#pragma unroll
      for (int p = 0; p < 12; ++p)
        orow[128 + d * 96 + h * 12 + p] = accp[p * 3 + d] * inv;
  }
}

// ---------------------------------------------------------------------------
extern "C" void kernel_launch(void* const* d_in, const int* in_sizes, int n_in,
                              void* d_out, int out_size, void* d_ws, size_t ws_size,
                              hipStream_t stream) {
  const float* s     = (const float*)d_in[0];
  const float* z     = (const float*)d_in[1];
  const float* rot   = (const float*)d_in[2];
  const float* trans = (const float*)d_in[3];
  const float* L     = (const float*)d_in[4];
  const float* Wq    = (const float*)d_in[5];
  const float* bq    = (const float*)d_in[6];
  const float* Wkv   = (const float*)d_in[7];
  const float* bkv   = (const float*)d_in[8];
  const float* Wqp   = (const float*)d_in[9];
  const float* bqp   = (const float*)d_in[10];
  const float* Wkvp  = (const float*)d_in[11];
  const float* bkvp  = (const float*)d_in[12];
  const float* Wb    = (const float*)d_in[13];
  const float* bb    = (const float*)d_in[14];
  const float* Wl    = (const float*)d_in[15];
  const float* bl    = (const float*)d_in[16];
  const float* hwts  = (const float*)d_in[17];
  const float* Wout  = (const float*)d_in[18];
  const float* bout  = (const float*)d_in[19];
  float* out = (float*)d_out;
  float* ws  = (float*)d_ws;

  // workspace layout (floats)
  float* praw  = ws;                    // [M,1056]   3244032
  float* qpts  = praw  + 3244032;       // [M,8,8,3]   589824
  float* kpts  = qpts  + 589824;        //             589824
  float* vpts  = kpts  + 589824;        // [M,8,12,3]  884736
  float* ofeat = vpts  + 884736;        // [M,432]    1327104
  float* bT2   = ofeat + 1327104;       // [8,B,96,96] 2359296 (natural [h][b][i][j])

  proj_bpair<<<GEMM_BLOCKS + M_, 256, 0, stream>>>(s, Wq, Wkv, Wqp, Wkvp,
                                                   bq, bkv, bqp, bkvp,
                                                   z, Wb, bb, praw, bT2);
  rotate_pts<<<M_, 256, 0, stream>>>(praw, rot, trans, L, qpts, kpts, vpts, ofeat);
  attn_kernel<<<256, 768, 0, stream>>>(praw, qpts, kpts, vpts, bT2, L, Wl, bl, hwts, ofeat);
  gemm64<true ><<<dim3(4, 48), 256, 0, stream>>>(ofeat, Wout, bout, out, 256, OF_, 422);
}

// Round 15
// 353.105 us; speedup vs baseline: 1.0972x; 1.0387x over previous
//
#include <hip/hip_runtime.h>
#include <math.h>

#define B_    32
#define NPER_ 96
#define M_    3072
#define H_    8
#define CH_   16
#define PQK_  8
#define PV_   12
#define CS_   256
#define CZ_   128
#define E_    294912
#define NCAT_ 1056
#define OF_   432   // padded o_feats row stride (422 real cols)
#define GEMM_BLOCKS 816   // 17 col-tiles x 48 row-tiles

// ---------------------------------------------------------------------------
// Tiled f32 GEMM (64x64): C[M,N] = A[M,K] @ W[K,N] + bias[N]. W rows >= KW -> 0.
// Used for the output projection.
// ---------------------------------------------------------------------------
template <bool ALIGN_A>
__global__ __launch_bounds__(256) void gemm64(const float* __restrict__ A,
                                              const float* __restrict__ W,
                                              const float* __restrict__ bias,
                                              float* __restrict__ C,
                                              int N, int K, int KW) {
  __shared__ float As[16][68];
  __shared__ float Bs[16][64];
  const int tid = threadIdx.x;
  const int tx = tid & 15, ty = tid >> 4;
  const int row0 = blockIdx.y * 64, col0 = blockIdx.x * 64;
  float acc[4][4] = {};

  for (int k0 = 0; k0 < K; k0 += 16) {
    {
      const int m = tid >> 2, k4 = (tid & 3) * 4;
      const int gk = k0 + k4;
      float a0 = 0.f, a1 = 0.f, a2 = 0.f, a3 = 0.f;
      if (ALIGN_A) {
        const float4 av = *reinterpret_cast<const float4*>(A + (size_t)(row0 + m) * K + gk);
        a0 = av.x; a1 = av.y; a2 = av.z; a3 = av.w;
      } else {
        const float* ap = A + (size_t)(row0 + m) * K;
        if (gk + 0 < K) a0 = ap[gk + 0];
        if (gk + 1 < K) a1 = ap[gk + 1];
        if (gk + 2 < K) a2 = ap[gk + 2];
        if (gk + 3 < K) a3 = ap[gk + 3];
      }
      As[k4 + 0][m] = a0; As[k4 + 1][m] = a1; As[k4 + 2][m] = a2; As[k4 + 3][m] = a3;
    }
    {
      const int kk = tid >> 4, n4 = (tid & 15) * 4;
      const int gk = k0 + kk, gn = col0 + n4;
      float4 bv; bv.x = 0.f; bv.y = 0.f; bv.z = 0.f; bv.w = 0.f;
      if (gk < KW) {
        if (gn + 3 < N) {
          bv = *reinterpret_cast<const float4*>(W + (size_t)gk * N + gn);
        } else {
          const float* wp = W + (size_t)gk * N;
          if (gn + 0 < N) bv.x = wp[gn + 0];
          if (gn + 1 < N) bv.y = wp[gn + 1];
          if (gn + 2 < N) bv.z = wp[gn + 2];
          if (gn + 3 < N) bv.w = wp[gn + 3];
        }
      }
      *reinterpret_cast<float4*>(&Bs[kk][n4]) = bv;
    }
    __syncthreads();
#pragma unroll
    for (int kk = 0; kk < 16; ++kk) {
      const float4 a_ = *reinterpret_cast<const float4*>(&As[kk][ty * 4]);
      const float4 b_ = *reinterpret_cast<const float4*>(&Bs[kk][tx * 4]);
      acc[0][0] += a_.x * b_.x; acc[0][1] += a_.x * b_.y; acc[0][2] += a_.x * b_.z; acc[0][3] += a_.x * b_.w;
      acc[1][0] += a_.y * b_.x; acc[1][1] += a_.y * b_.y; acc[1][2] += a_.y * b_.z; acc[1][3] += a_.y * b_.w;
      acc[2][0] += a_.z * b_.x; acc[2][1] += a_.z * b_.y; acc[2][2] += a_.z * b_.z; acc[2][3] += a_.z * b_.w;
      acc[3][0] += a_.w * b_.x; acc[3][1] += a_.w * b_.y; acc[3][2] += a_.w * b_.z; acc[3][3] += a_.w * b_.w;
    }
    __syncthreads();
  }
  const int gn0 = col0 + tx * 4;
#pragma unroll
  for (int i2 = 0; i2 < 4; ++i2) {
    const int gr = row0 + ty * 4 + i2;
    if (gn0 + 3 < N) {
      const float4 bsv = *reinterpret_cast<const float4*>(bias + gn0);
      float4 cv;
      cv.x = acc[i2][0] + bsv.x; cv.y = acc[i2][1] + bsv.y;
      cv.z = acc[i2][2] + bsv.z; cv.w = acc[i2][3] + bsv.w;
      *reinterpret_cast<float4*>(C + (size_t)gr * N + gn0) = cv;
    } else {
#pragma unroll
      for (int j2 = 0; j2 < 4; ++j2) {
        const int gn = gn0 + j2;
        if (gn < N) C[(size_t)gr * N + gn] = acc[i2][j2] + bias[gn];
      }
    }
  }
}

// ---------------------------------------------------------------------------
// Fused kernel: blocks [0,816) = projection GEMM; blocks [816,816+3072) =
// bpair. bpair path: wave covers 2 z-rows/iter via float4 loads (1024 B
// coalesced), 32-lane head-specializing butterfly (xor1/2/4 select levels +
// xor8/16 adds), compiler-pipelined loop (no unroll pin).
// ---------------------------------------------------------------------------
__global__ __launch_bounds__(256) void proj_bpair(const float* __restrict__ s,
                                                  const float* __restrict__ Wq,
                                                  const float* __restrict__ Wkv,
                                                  const float* __restrict__ Wqp,
                                                  const float* __restrict__ Wkvp,
                                                  const float* __restrict__ bq,
                                                  const float* __restrict__ bkv,
                                                  const float* __restrict__ bqp,
                                                  const float* __restrict__ bkvp,
                                                  const float* __restrict__ z,
                                                  const float* __restrict__ Wb,
                                                  const float* __restrict__ bb,
                                                  float* __restrict__ praw,
                                                  float* __restrict__ bT2) {
  __shared__ float smem[16 * 68 + 16 * 64];
  const int bid = blockIdx.x;
  const int tid = threadIdx.x;

  if (bid < GEMM_BLOCKS) {
    // ---------------- projection GEMM path ----------------
    float (*As)[68] = reinterpret_cast<float(*)[68]>(smem);
    float (*Bs)[64] = reinterpret_cast<float(*)[64]>(smem + 16 * 68);
    const int cb = bid % 17, rb = bid / 17;
    const int row0 = rb * 64, col0 = cb * 64;
    const float* Wsrc; const float* bsrc; int Nsrc, cbase;
    if (col0 < 128)      { Wsrc = Wq;   bsrc = bq;   Nsrc = 128; cbase = 0; }
    else if (col0 < 384) { Wsrc = Wkv;  bsrc = bkv;  Nsrc = 256; cbase = 128; }
    else if (col0 < 576) { Wsrc = Wqp;  bsrc = bqp;  Nsrc = 192; cbase = 384; }
    else                 { Wsrc = Wkvp; bsrc = bkvp; Nsrc = 480; cbase = 576; }
    const int csrc0 = col0 - cbase;
    const int tx = tid & 15, ty = tid >> 4;
    float acc[4][4] = {};

    for (int k0 = 0; k0 < 256; k0 += 16) {
      {
        const int m = tid >> 2, k4 = (tid & 3) * 4;
        const float4 av = *reinterpret_cast<const float4*>(s + (size_t)(row0 + m) * 256 + k0 + k4);
        As[k4 + 0][m] = av.x; As[k4 + 1][m] = av.y; As[k4 + 2][m] = av.z; As[k4 + 3][m] = av.w;
      }
      {
        const int kk = tid >> 4, n4 = (tid & 15) * 4;
        const int gnl = csrc0 + n4;  // Nsrc % 4 == 0 -> float4 fully in or out
        float4 bv; bv.x = 0.f; bv.y = 0.f; bv.z = 0.f; bv.w = 0.f;
        if (gnl < Nsrc) bv = *reinterpret_cast<const float4*>(Wsrc + (size_t)(k0 + kk) * Nsrc + gnl);
        *reinterpret_cast<float4*>(&Bs[kk][n4]) = bv;
      }
      __syncthreads();
#pragma unroll
      for (int kk = 0; kk < 16; ++kk) {
        const float4 a_ = *reinterpret_cast<const float4*>(&As[kk][ty * 4]);
        const float4 b_ = *reinterpret_cast<const float4*>(&Bs[kk][tx * 4]);
        acc[0][0] += a_.x * b_.x; acc[0][1] += a_.x * b_.y; acc[0][2] += a_.x * b_.z; acc[0][3] += a_.x * b_.w;
        acc[1][0] += a_.y * b_.x; acc[1][1] += a_.y * b_.y; acc[1][2] += a_.y * b_.z; acc[1][3] += a_.y * b_.w;
        acc[2][0] += a_.z * b_.x; acc[2][1] += a_.z * b_.y; acc[2][2] += a_.z * b_.z; acc[2][3] += a_.z * b_.w;
        acc[3][0] += a_.w * b_.x; acc[3][1] += a_.w * b_.y; acc[3][2] += a_.w * b_.z; acc[3][3] += a_.w * b_.w;
      }
      __syncthreads();
    }
    const int gnl0 = csrc0 + tx * 4;
    if (gnl0 < Nsrc) {
      const float4 bsv = *reinterpret_cast<const float4*>(bsrc + gnl0);
#pragma unroll
      for (int i2 = 0; i2 < 4; ++i2) {
        const int gr = row0 + ty * 4 + i2;
        float4 cv;
        cv.x = acc[i2][0] + bsv.x; cv.y = acc[i2][1] + bsv.y;
        cv.z = acc[i2][2] + bsv.z; cv.w = acc[i2][3] + bsv.w;
        *reinterpret_cast<float4*>(praw + (size_t)gr * NCAT_ + col0 + tx * 4) = cv;
      }
    }
  } else {
    // ---------------- bpair path (float4, 2 rows/wave-iter) ----------------
    float* lds_out = smem;
    const int eb = bid - GEMM_BLOCKS;
    const int b = eb / 96, i = eb - b * 96;
    const int l = tid & 63;
    const int w = tid >> 6;            // wave 0..3
    const int half = l >> 5;           // row parity within the pair
    const int c = l & 31;              // float4 index within the row
    // per-lane weights: Wb rows 4c..4c+3, heads 0..3 (a) and 4..7 (b)
    const float4* Wb4 = reinterpret_cast<const float4*>(Wb);
    const float4 w0a = Wb4[(4 * c + 0) * 2 + 0], w0b = Wb4[(4 * c + 0) * 2 + 1];
    const float4 w1a = Wb4[(4 * c + 1) * 2 + 0], w1b = Wb4[(4 * c + 1) * 2 + 1];
    const float4 w2a = Wb4[(4 * c + 2) * 2 + 0], w2b = Wb4[(4 * c + 2) * 2 + 1];
    const float4 w3a = Wb4[(4 * c + 3) * 2 + 0], w3b = Wb4[(4 * c + 3) * 2 + 1];
    const int b0 = c & 1, b1 = (c >> 1) & 1, b2 = (c >> 2) & 1;
    const int myh = (b0 << 2) | (b1 << 1) | b2;
    const float mybb = bb[myh];
    const float4* z4 = reinterpret_cast<const float4*>(z);
    const size_t e0 = (size_t)b * 9216 + (size_t)i * 96;

    for (int t = 0; t < 12; ++t) {
      const int r0 = t * 8 + w * 2;                 // wave's row pair base
      const float4 zv = z4[(e0 + r0 + half) * 32 + c];
      float a0 = zv.x * w0a.x + zv.y * w1a.x + zv.z * w2a.x + zv.w * w3a.x;
      float a1 = zv.x * w0a.y + zv.y * w1a.y + zv.z * w2a.y + zv.w * w3a.y;
      float a2 = zv.x * w0a.z + zv.y * w1a.z + zv.z * w2a.z + zv.w * w3a.z;
      float a3 = zv.x * w0a.w + zv.y * w1a.w + zv.z * w2a.w + zv.w * w3a.w;
      float a4 = zv.x * w0b.x + zv.y * w1b.x + zv.z * w2b.x + zv.w * w3b.x;
      float a5 = zv.x * w0b.y + zv.y * w1b.y + zv.z * w2b.y + zv.w * w3b.y;
      float a6 = zv.x * w0b.z + zv.y * w1b.z + zv.z * w2b.z + zv.w * w3b.z;
      float a7 = zv.x * w0b.w + zv.y * w1b.w + zv.z * w2b.w + zv.w * w3b.w;
      // level 1 (xor 1): 8 -> 4, lane keeps heads selected by b0
      float s40 = (b0 ? a4 : a0) + __shfl_xor(b0 ? a0 : a4, 1);
      float s41 = (b0 ? a5 : a1) + __shfl_xor(b0 ? a1 : a5, 1);
      float s42 = (b0 ? a6 : a2) + __shfl_xor(b0 ? a2 : a6, 1);
      float s43 = (b0 ? a7 : a3) + __shfl_xor(b0 ? a3 : a7, 1);
      // level 2 (xor 2): 4 -> 2 by b1
      float s20 = (b1 ? s42 : s40) + __shfl_xor(b1 ? s40 : s42, 2);
      float s21 = (b1 ? s43 : s41) + __shfl_xor(b1 ? s41 : s43, 2);
      // level 3 (xor 4): 2 -> 1 by b2
      float s1 = (b2 ? s21 : s20) + __shfl_xor(b2 ? s20 : s21, 4);
      // plain adds across remaining lane groups (within the 32-lane half)
      s1 += __shfl_xor(s1, 8);
      s1 += __shfl_xor(s1, 16);
      if (c < 8) lds_out[(r0 + half) * 9 + myh] = s1 + mybb;
    }
    __syncthreads();
    for (int idx = tid; idx < 768; idx += 256) {
      const int h = idx / 96, j = idx - h * 96;
      bT2[(size_t)h * E_ + e0 + j] = lds_out[j * 9 + h];
    }
  }
}

// ---------------------------------------------------------------------------
// Rotate raw point projections into global frame; seed o_feats L columns.
// ---------------------------------------------------------------------------
__global__ __launch_bounds__(256) void rotate_pts(const float* __restrict__ praw,
                                                  const float* __restrict__ rot,
                                                  const float* __restrict__ trans,
                                                  const float* __restrict__ L,
                                                  float* __restrict__ qpts,
                                                  float* __restrict__ kpts,
                                                  float* __restrict__ vpts,
                                                  float* __restrict__ ofeat) {
  const int m = blockIdx.x;
  const int t = threadIdx.x;
  float R[9], T[3];
#pragma unroll
  for (int a = 0; a < 9; ++a) R[a] = rot[m * 9 + a];
#pragma unroll
  for (int a = 0; a < 3; ++a) T[a] = trans[m * 3 + a];
  const float* prow = praw + (size_t)m * NCAT_;

  if (t < 64) {
    const float x = prow[384 + t];
    const float y = prow[384 + 64 + t];
    const float z = prow[384 + 128 + t];
    const int h = t >> 3, p = t & 7;
    float* dst = qpts + ((size_t)(m * 8 + h) * 8 + p) * 3;
    dst[0] = R[0] * x + R[1] * y + R[2] * z + T[0];
    dst[1] = R[3] * x + R[4] * y + R[5] * z + T[1];
    dst[2] = R[6] * x + R[7] * y + R[8] * z + T[2];
  } else if (t < 224) {
    const int idx = t - 64;
    const float x = prow[576 + idx];
    const float y = prow[576 + 160 + idx];
    const float z = prow[576 + 320 + idx];
    const int h = idx / 20, p = idx % 20;
    const float o0 = R[0] * x + R[1] * y + R[2] * z + T[0];
    const float o1 = R[3] * x + R[4] * y + R[5] * z + T[1];
    const float o2 = R[6] * x + R[7] * y + R[8] * z + T[2];
    float* dst = (p < 8) ? (kpts + ((size_t)(m * 8 + h) * 8 + p) * 3)
                         : (vpts + ((size_t)(m * 8 + h) * 12 + (p - 8)) * 3);
    dst[0] = o0; dst[1] = o1; dst[2] = o2;
  } else if (t < 230) {
    ofeat[(size_t)m * OF_ + 416 + (t - 224)] = L[(m / NPER_) * 6 + (t - 224)];
  }
}

// ---------------------------------------------------------------------------
// Attention: one block per (batch, head). 768 threads = 96 rows x 8 lanes.
// Bias tile [i][j] staged contiguous (36 KB); read lds_b[i*100+j] (2-way free).
// ---------------------------------------------------------------------------
__global__ __launch_bounds__(768, 3) void attn_kernel(const float* __restrict__ praw,
                                                      const float* __restrict__ qpts,
                                                      const float* __restrict__ kpts,
                                                      const float* __restrict__ vpts,
                                                      const float* __restrict__ bT2,
                                                      const float* __restrict__ L,
                                                      const float* __restrict__ Wl,
                                                      const float* __restrict__ bl,
                                                      const float* __restrict__ hwts,
                                                      float* __restrict__ ofeat) {
  const int b = blockIdx.x >> 3, h = blockIdx.x & 7;
  __shared__ float4 k4[96 * 5];
  __shared__ float4 v4[96 * 5];
  __shared__ float4 kp4[96 * 6];
  __shared__ float4 vp4[96 * 9];
  __shared__ float lds_b[96 * 100];
  const int tid = threadIdx.x;

  {  // k/v: 96 rows x 8 float4, one per thread
    const int i = tid >> 3, c = tid & 7;
    const float4* src = reinterpret_cast<const float4*>(praw + (size_t)(b * 96 + i) * NCAT_ + 128 + h * 32);
    if (c < 4) k4[i * 5 + c] = src[c];
    else       v4[i * 5 + (c - 4)] = src[c];
  }
  for (int t = tid; t < 96 * 6; t += 768) {
    const int i = t / 6, c = t - i * 6;
    kp4[t] = reinterpret_cast<const float4*>(kpts + ((size_t)(b * 96 + i) * 8 + h) * 24)[c];
  }
  for (int t = tid; t < 96 * 9; t += 768) {
    const int i = t / 9, c = t - i * 9;
    vp4[t] = reinterpret_cast<const float4*>(vpts + ((size_t)(b * 96 + i) * 8 + h) * 36)[c];
  }
  {  // bias tile: 9216 floats contiguous [i][j] -> lds_b[i*100 + j]
    const float4* g4 = reinterpret_cast<const float4*>(bT2 + (size_t)h * E_ + (size_t)b * 9216);
    for (int t = tid; t < 2304; t += 768) {
      const int ii = t / 24, c = t - ii * 24;
      reinterpret_cast<float4*>(lds_b + ii * 100)[c] = g4[t];
    }
  }
  __syncthreads();

  const int j = tid >> 3, qq = tid & 7;
  const int mj = b * 96 + j;

  float lb = bl[h];
#pragma unroll
  for (int d = 0; d < 6; ++d) lb += L[b * 6 + d] * Wl[d * 8 + h];
  const float c_l = 0.5f * lb;
  const float sp = logf(1.0f + __expf(hwts[h]));
  const float c_pt = 0.5f * sp * (1.0f / 12.0f);

  const float4* q4 = reinterpret_cast<const float4*>(praw + (size_t)mj * NCAT_ + h * 16);
  const float4 qa = q4[0], qb = q4[1], qc = q4[2], qd = q4[3];
  float qp[24];
  {
    const float4* qp4 = reinterpret_cast<const float4*>(qpts + ((size_t)mj * 8 + h) * 24);
#pragma unroll
    for (int c4 = 0; c4 < 6; ++c4) {
      const float4 v_ = qp4[c4];
      qp[c4 * 4 + 0] = v_.x; qp[c4 * 4 + 1] = v_.y; qp[c4 * 4 + 2] = v_.z; qp[c4 * 4 + 3] = v_.w;
    }
  }

  float lg[12];
  float mx = -3.0e38f;
#pragma unroll
  for (int s = 0; s < 12; ++s) {
    const int i = s * 8 + qq;
    const float4 ka = k4[i * 5 + 0], kb = k4[i * 5 + 1], kc = k4[i * 5 + 2], kd = k4[i * 5 + 3];
    float dot = qa.x * ka.x + qa.y * ka.y + qa.z * ka.z + qa.w * ka.w
              + qb.x * kb.x + qb.y * kb.y + qb.z * kb.z + qb.w * kb.w
              + qc.x * kc.x + qc.y * kc.y + qc.z * kc.z + qc.w * kc.w
              + qd.x * kd.x + qd.y * kd.y + qd.z * kd.z + qd.w * kd.w;
    float pd = 0.f;
#pragma unroll
    for (int c4 = 0; c4 < 6; ++c4) {
      const float4 kp = kp4[i * 6 + c4];
      const float d0 = qp[c4 * 4 + 0] - kp.x;
      const float d1 = qp[c4 * 4 + 1] - kp.y;
      const float d2 = qp[c4 * 4 + 2] - kp.z;
      const float d3 = qp[c4 * 4 + 3] - kp.w;
      pd += d0 * d0 + d1 * d1 + d2 * d2 + d3 * d3;
    }
    const float lv = dot * 0.125f + 0.5f * lds_b[i * 100 + j] + c_l - c_pt * pd;
    lg[s] = lv;
    mx = fmaxf(mx, lv);
  }
  mx = fmaxf(mx, __shfl_xor(mx, 1));
  mx = fmaxf(mx, __shfl_xor(mx, 2));
  mx = fmaxf(mx, __shfl_xor(mx, 4));
  float sum = 0.f;
#pragma unroll
  for (int s = 0; s < 12; ++s) { lg[s] = __expf(lg[s] - mx); sum += lg[s]; }
  sum += __shfl_xor(sum, 1);
  sum += __shfl_xor(sum, 2);
  sum += __shfl_xor(sum, 4);
  const float inv = 1.0f / sum;

  float acco[16] = {};
  float accp[36] = {};
#pragma unroll
  for (int s = 0; s < 12; ++s) {
    const int i = s * 8 + qq;
    const float w = lg[s];
#pragma unroll
    for (int c4 = 0; c4 < 4; ++c4) {
      const float4 vv = v4[i * 5 + c4];
      acco[c4 * 4 + 0] += w * vv.x; acco[c4 * 4 + 1] += w * vv.y;
      acco[c4 * 4 + 2] += w * vv.z; acco[c4 * 4 + 3] += w * vv.w;
    }
#pragma unroll
    for (int c4 = 0; c4 < 9; ++c4) {
      const float4 pv = vp4[i * 9 + c4];
      accp[c4 * 4 + 0] += w * pv.x; accp[c4 * 4 + 1] += w * pv.y;
      accp[c4 * 4 + 2] += w * pv.z; accp[c4 * 4 + 3] += w * pv.w;
    }
  }
#pragma unroll
  for (int u = 0; u < 16; ++u) {
    acco[u] += __shfl_xor(acco[u], 1); acco[u] += __shfl_xor(acco[u], 2); acco[u] += __shfl_xor(acco[u], 4);
  }
#pragma unroll
  for (int u = 0; u < 36; ++u) {
    accp[u] += __shfl_xor(accp[u], 1); accp[u] += __shfl_xor(accp[u], 2); accp[u] += __shfl_xor(accp[u], 4);
  }

  if (qq == 0) {
    float* orow = ofeat + (size_t)mj * OF_;
#pragma unroll
    for (int c = 0; c < 16; ++c) orow[h * 16 + c] = acco[c] * inv;
#pragma unroll
    for (int d = 0; d < 3; ++d)
#pragma unroll
      for (int p = 0; p < 12; ++p)
        orow[128 + d * 96 + h * 12 + p] = accp[p * 3 + d] * inv;
  }
}

// ---------------------------------------------------------------------------
extern "C" void kernel_launch(void* const* d_in, const int* in_sizes, int n_in,
                              void* d_out, int out_size, void* d_ws, size_t ws_size,
                              hipStream_t stream) {
  const float* s     = (const float*)d_in[0];
  const float* z     = (const float*)d_in[1];
  const float* rot   = (const float*)d_in[2];
  const float* trans = (const float*)d_in[3];
  const float* L     = (const float*)d_in[4];
  const float* Wq    = (const float*)d_in[5];
  const float* bq    = (const float*)d_in[6];
  const float* Wkv   = (const float*)d_in[7];
  const float* bkv   = (const float*)d_in[8];
  const float* Wqp   = (const float*)d_in[9];
  const float* bqp   = (const float*)d_in[10];
  const float* Wkvp  = (const float*)d_in[11];
  const float* bkvp  = (const float*)d_in[12];
  const float* Wb    = (const float*)d_in[13];
  const float* bb    = (const float*)d_in[14];
  const float* Wl    = (const float*)d_in[15];
  const float* bl    = (const float*)d_in[16];
  const float* hwts  = (const float*)d_in[17];
  const float* Wout  = (const float*)d_in[18];
  const float* bout  = (const float*)d_in[19];
  float* out = (float*)d_out;
  float* ws  = (float*)d_ws;

  // workspace layout (floats)
  float* praw  = ws;                    // [M,1056]   3244032
  float* qpts  = praw  + 3244032;       // [M,8,8,3]   589824
  float* kpts  = qpts  + 589824;        //             589824
  float* vpts  = kpts  + 589824;        // [M,8,12,3]  884736
  float* ofeat = vpts  + 884736;        // [M,432]    1327104
  float* bT2   = ofeat + 1327104;       // [8,B,96,96] 2359296 (natural [h][b][i][j])

  proj_bpair<<<GEMM_BLOCKS + M_, 256, 0, stream>>>(s, Wq, Wkv, Wqp, Wkvp,
                                                   bq, bkv, bqp, bkvp,
                                                   z, Wb, bb, praw, bT2);
  rotate_pts<<<M_, 256, 0, stream>>>(praw, rot, trans, L, qpts, kpts, vpts, ofeat);
  attn_kernel<<<256, 768, 0, stream>>>(praw, qpts, kpts, vpts, bT2, L, Wl, bl, hwts, ofeat);
  gemm64<true ><<<dim3(4, 48), 256, 0, stream>>>(ofeat, Wout, bout, out, 256, OF_, 422);
}